// Round 12
// baseline (1093.024 us; speedup 1.0000x reference)
//
#include <hip/hip_runtime.h>
#include <stdint.h>

#define B_ 2
#define S_ 2048
#define D_ 4096
#define H_ 32
#define KV_ 8
#define HD_ 128
#define M_ (B_*S_)          // 4096 rows (b*S+s)
#define NQ_ (H_*HD_)        // 4096
#define NKV_ (KV_*HD_)      // 1024

typedef unsigned short u16;
typedef __bf16 bf16x8 __attribute__((ext_vector_type(8)));
typedef float f32x4 __attribute__((ext_vector_type(4)));
typedef u16 u16x8 __attribute__((ext_vector_type(8)));
typedef u16 u16x4 __attribute__((ext_vector_type(4)));

__device__ __forceinline__ u16 f2bf(float f) {
  union { float f; unsigned u; } v; v.f = f;
  unsigned r = v.u + 0x7fffu + ((v.u >> 16) & 1u);
  return (u16)(r >> 16);
}
__device__ __forceinline__ u16 f2bft(float f) {  // truncating (for P; values in [0,4.2])
  union { float f; unsigned u; } v; v.f = f;
  return (u16)(v.u >> 16);
}
__device__ __forceinline__ float bf2f(u16 u) {
  union { unsigned u; float f; } v; v.u = ((unsigned)u) << 16;
  return v.f;
}
__device__ __forceinline__ f32x4 mfma16(bf16x8 a, bf16x8 b, f32x4 c) {
  return __builtin_amdgcn_mfma_f32_16x16x32_bf16(a, b, c, 0, 0, 0);
}

#define GLDS16(gp, lp) __builtin_amdgcn_global_load_lds( \
    (const __attribute__((address_space(1))) unsigned int*)(gp), \
    (__attribute__((address_space(3))) unsigned int*)(lp), 16, 0, 0)

// ---------------- fp32 -> bf16 convert (vectorized) ----------------
__global__ __launch_bounds__(256) void cvt_bf16(const float* __restrict__ in,
                                                u16* __restrict__ out, int n) {
  int i = (blockIdx.x * 256 + threadIdx.x) * 8;
  if (i >= n) return;
  float4 a = *(const float4*)(in + i);
  float4 b = *(const float4*)(in + i + 4);
  u16x8 o;
  o[0]=f2bf(a.x); o[1]=f2bf(a.y); o[2]=f2bf(a.z); o[3]=f2bf(a.w);
  o[4]=f2bf(b.x); o[5]=f2bf(b.y); o[6]=f2bf(b.z); o[7]=f2bf(b.w);
  *(u16x8*)(out + i) = o;
}

// -------- transpose + convert: out[c][r] = in[r][c], 64x64, vectorized --------
__global__ __launch_bounds__(256) void tcvt(const float* __restrict__ in,
                                            u16* __restrict__ out, int R, int C) {
  __shared__ float tf[64][65];
  int c0 = blockIdx.x * 64, r0 = blockIdx.y * 64;
  int l16 = threadIdx.x & 15, r16 = threadIdx.x >> 4;
  #pragma unroll
  for (int p = 0; p < 4; ++p) {
    int r = p * 16 + r16;
    float4 v = *(const float4*)(in + (size_t)(r0 + r) * C + c0 + l16 * 4);
    tf[r][l16 * 4 + 0] = v.x; tf[r][l16 * 4 + 1] = v.y;
    tf[r][l16 * 4 + 2] = v.z; tf[r][l16 * 4 + 3] = v.w;
  }
  __syncthreads();
  int oc = threadIdx.x >> 2, ch = threadIdx.x & 3;
  u16x8 o1, o2;
  #pragma unroll
  for (int i = 0; i < 8; ++i) o1[i] = f2bf(tf[ch * 16 + i][oc]);
  #pragma unroll
  for (int i = 0; i < 8; ++i) o2[i] = f2bf(tf[ch * 16 + 8 + i][oc]);
  *(u16x8*)(out + (size_t)(c0 + oc) * R + r0 + ch * 16) = o1;
  *(u16x8*)(out + (size_t)(c0 + oc) * R + r0 + ch * 16 + 8) = o2;
}

// ------- 256x256 GEMM, 3-buf rotation + FULL cross-tile register pipeline -------
// (unchanged from R10; ~1015 TF, sync-economics-capped at this geometry.)
template<int OUTMODE>
__global__ __launch_bounds__(512, 2) void gemm256(const u16* __restrict__ A,
    const u16* __restrict__ BT, void* __restrict__ Cv, int M, int N, int K) {
  extern __shared__ __attribute__((aligned(16))) u16 DL[];  // 3 x 16384 u16
  const int tid = threadIdx.x;
  const int nbx = N >> 8;
  const int cpx = gridDim.x >> 3;                 // grid % 8 == 0
  const int swzb = (blockIdx.x & 7) * cpx + (blockIdx.x >> 3);
  const int bn0 = (swzb % nbx) << 8, bm0 = (swzb / nbx) << 8;
  const int l = tid & 63, g = l >> 4, q = l & 15;
  const int w = tid >> 6;
  const int wm = (w >> 2) * 128, wn = (w & 3) * 64;
  const int nt = K >> 5;   // BK = 32
  f32x4 acc[8][4] = {};

  const int srow = tid >> 2, schunk = tid & 3;
  const int ssw = (schunk ^ ((srow >> 1) & 3)) << 3;
  const u16* gA0 = A  + (size_t)(bm0 + srow) * K + ssw;
  const u16* gA1 = gA0 + (size_t)128 * K;
  const u16* gB0 = BT + (size_t)(bn0 + srow) * K + ssw;
  const u16* gB1 = gB0 + (size_t)128 * K;

  auto STAGE = [&](int t) {
    const int kt = t << 5;
    u16* d = DL + (t % 3) * 16384;
    GLDS16(gA0 + kt, d + tid * 8);
    GLDS16(gA1 + kt, d + 4096 + tid * 8);
    GLDS16(gB0 + kt, d + 8192 + tid * 8);
    GLDS16(gB1 + kt, d + 12288 + tid * 8);
  };

  const u16* ra = DL + (wm + q) * 32 + ((g ^ (((wm + q) >> 1) & 3)) << 3);
  const u16* rb = DL + 8192 + (wn + q) * 32 + ((g ^ (((wn + q) >> 1) & 3)) << 3);

  bf16x8 aC[8], aN[8], bC[4], bN[4];

  STAGE(0); STAGE(1);
  asm volatile("s_waitcnt vmcnt(4)" ::: "memory");
  __builtin_amdgcn_s_barrier();
  #pragma unroll
  for (int m = 0; m < 8; ++m) aC[m] = *(const bf16x8*)(ra + m * 512);
  #pragma unroll
  for (int n = 0; n < 4; ++n) bC[n] = *(const bf16x8*)(rb + n * 512);

  auto TILE = [&](int t, bf16x8 (&ac)[8], bf16x8 (&bc)[4],
                         bf16x8 (&an)[8], bf16x8 (&bn)[4]) {
    if (t + 2 < nt) {
      STAGE(t + 2);
      asm volatile("s_waitcnt vmcnt(4)" ::: "memory");
    } else {
      asm volatile("s_waitcnt vmcnt(0)" ::: "memory");
    }
    __builtin_amdgcn_s_barrier();
    if (t + 1 < nt) {
      const u16* pa = ra + ((t + 1) % 3) * 16384;
      const u16* pb = rb + ((t + 1) % 3) * 16384;
      #pragma unroll
      for (int m = 0; m < 8; ++m) an[m] = *(const bf16x8*)(pa + m * 512);
      #pragma unroll
      for (int n = 0; n < 4; ++n) bn[n] = *(const bf16x8*)(pb + n * 512);
    }
    __builtin_amdgcn_s_setprio(1);
    #pragma unroll
    for (int m = 0; m < 8; ++m) {
      acc[m][0] = mfma16(ac[m], bc[0], acc[m][0]);
      acc[m][1] = mfma16(ac[m], bc[1], acc[m][1]);
      acc[m][2] = mfma16(ac[m], bc[2], acc[m][2]);
      acc[m][3] = mfma16(ac[m], bc[3], acc[m][3]);
    }
    __builtin_amdgcn_s_setprio(0);
  };

  for (int t = 0; t < nt; t += 2) {
    TILE(t,     aC, bC, aN, bN);
    TILE(t + 1, aN, bN, aC, bC);
  }

  #pragma unroll
  for (int m = 0; m < 8; ++m)
    #pragma unroll
    for (int n = 0; n < 4; ++n)
      #pragma unroll
      for (int j = 0; j < 4; ++j) {
        size_t off = (size_t)(bm0 + wm + m * 16 + g * 4 + j) * N + (bn0 + wn + n * 16 + q);
        if (OUTMODE == 1) ((float*)Cv)[off] = acc[m][n][j];
        else              ((u16*)Cv)[off]  = f2bf(acc[m][n][j]);
      }
}

// ------- KV projection GEMM: BM=256 x BN=128, same 3-buf reg pipeline -------
__global__ __launch_bounds__(512, 2) void gemm_kv(const u16* __restrict__ A,
    const u16* __restrict__ BT, u16* __restrict__ Ck, u16* __restrict__ Cvt,
    int M, int N, int K) {
  extern __shared__ __attribute__((aligned(16))) u16 DL[];  // 3 x 12288 u16
  const int tid = threadIdx.x;
  const int nbx = N >> 7;                          // 16
  const int cpx = gridDim.x >> 3;
  const int swzb = (blockIdx.x & 7) * cpx + (blockIdx.x >> 3);
  const int bn0 = (swzb % nbx) << 7, bm0 = (swzb / nbx) << 8;
  const int l = tid & 63, g = l >> 4, q = l & 15;
  const int w = tid >> 6;
  const int wm = (w >> 2) * 128, wn = (w & 3) * 32;
  const int nt = K >> 5;
  f32x4 acc[8][2] = {};

  const int srow = tid >> 2, schunk = tid & 3;
  const int ssw = (schunk ^ ((srow >> 1) & 3)) << 3;
  const u16* gA0 = A  + (size_t)(bm0 + srow) * K + ssw;
  const u16* gA1 = gA0 + (size_t)128 * K;
  const u16* gB0 = BT + (size_t)(bn0 + srow) * K + ssw;

  auto STAGE = [&](int t) {
    const int kt = t << 5;
    u16* d = DL + (t % 3) * 12288;
    GLDS16(gA0 + kt, d + tid * 8);
    GLDS16(gA1 + kt, d + 4096 + tid * 8);
    GLDS16(gB0 + kt, d + 8192 + tid * 8);
  };

  const u16* ra = DL + (wm + q) * 32 + ((g ^ (((wm + q) >> 1) & 3)) << 3);
  const u16* rb = DL + 8192 + (wn + q) * 32 + ((g ^ (((wn + q) >> 1) & 3)) << 3);

  bf16x8 aC[8], aN[8], bC[2], bN[2];

  STAGE(0); STAGE(1);
  asm volatile("s_waitcnt vmcnt(3)" ::: "memory");
  __builtin_amdgcn_s_barrier();
  #pragma unroll
  for (int m = 0; m < 8; ++m) aC[m] = *(const bf16x8*)(ra + m * 512);
  #pragma unroll
  for (int n = 0; n < 2; ++n) bC[n] = *(const bf16x8*)(rb + n * 512);

  auto TILE = [&](int t, bf16x8 (&ac)[8], bf16x8 (&bc)[2],
                         bf16x8 (&an)[8], bf16x8 (&bn)[2]) {
    if (t + 2 < nt) {
      STAGE(t + 2);
      asm volatile("s_waitcnt vmcnt(3)" ::: "memory");
    } else {
      asm volatile("s_waitcnt vmcnt(0)" ::: "memory");
    }
    __builtin_amdgcn_s_barrier();
    if (t + 1 < nt) {
      const u16* pa = ra + ((t + 1) % 3) * 12288;
      const u16* pb = rb + ((t + 1) % 3) * 12288;
      #pragma unroll
      for (int m = 0; m < 8; ++m) an[m] = *(const bf16x8*)(pa + m * 512);
      #pragma unroll
      for (int n = 0; n < 2; ++n) bn[n] = *(const bf16x8*)(pb + n * 512);
    }
    __builtin_amdgcn_s_setprio(1);
    #pragma unroll
    for (int m = 0; m < 8; ++m) {
      acc[m][0] = mfma16(ac[m], bc[0], acc[m][0]);
      acc[m][1] = mfma16(ac[m], bc[1], acc[m][1]);
    }
    __builtin_amdgcn_s_setprio(0);
  };

  for (int t = 0; t < nt; t += 2) {
    TILE(t,     aC, bC, aN, bN);
    TILE(t + 1, aN, bN, aC, bC);
  }

  #pragma unroll
  for (int m = 0; m < 8; ++m)
    #pragma unroll
    for (int n = 0; n < 2; ++n) {
      int row0 = bm0 + wm + m * 16 + g * 4;
      int col  = bn0 + wn + n * 16 + q;
      if (col < 1024) {
        #pragma unroll
        for (int j = 0; j < 4; ++j)
          Ck[(size_t)(row0 + j) * 1024 + col] = f2bf(acc[m][n][j]);
      } else {
        int c2 = col - 1024;
        u16x4 pk;
        #pragma unroll
        for (int j = 0; j < 4; ++j) pk[j] = f2bf(acc[m][n][j]);
        size_t off = ((size_t)((row0 >> 11) * KV_ + (c2 >> 7)) * 32 + ((row0 >> 6) & 31)) * 8192
                   + (size_t)(c2 & 127) * 64 + (row0 & 63);
        *(u16x4*)(Cvt + off) = pk;
      }
    }
}

// ---------------- RoPE (interleaved pairs, in-place on bf16) ----------------
__global__ __launch_bounds__(256) void rope_kernel(u16* __restrict__ t,
    const float* __restrict__ fc, const float* __restrict__ fs,
    int log2ppr, int total_pairs) {
  int i = blockIdx.x * 256 + threadIdx.x;
  if (i >= total_pairs) return;
  int fi = i & 63;
  int row = i >> log2ppr;           // b*S + s
  int pos = row & (S_ - 1);
  float c = fc[pos * 64 + fi], s = fs[pos * 64 + fi];
  unsigned* p = (unsigned*)(t + 2 * (size_t)i);
  unsigned v = *p;
  float x0 = bf2f((u16)(v & 0xffffu)), x1 = bf2f((u16)(v >> 16));
  float r0 = x0 * c - x1 * s, r1 = x0 * s + x1 * c;
  *p = (unsigned)f2bf(r0) | ((unsigned)f2bf(r1) << 16);
}

// ---------------- causal GQA flash attention (swapped-QK^T, KT=32) ----------------
// R11 insight: occupancy was GRID-limited (1024 blocks = 4/CU). Now grid
// (32, H, B) = 2048 blocks (one qt each, longest-first qt=31-bx, backfilled)
// x 8 blocks/CU capacity: KT=32 -> LDS 20KB (K [32][128] + V^T [128][32] +
// P 4x[16][32]), launch_bounds (256,8) caps VGPR 64 (R11 measured exactly 64
// with MORE live state). 32 waves/CU = max occupancy.
__global__ __launch_bounds__(256, 8) void attn_kernel(
    const u16* __restrict__ Qb, const u16* __restrict__ Kb,
    const u16* __restrict__ VTg, u16* __restrict__ Ob) {
  __shared__ __attribute__((aligned(16))) u16 SM[10240]; // 20KB
  u16* Ks = SM;            // [32][128] swz chunk16B ^(row&7)
  u16* Vs = SM + 4096;     // [128][32] swz chunk16B ^(row&3)
  u16* Ps = SM + 8192;     // 4 waves x [16 q][32 k], chunk16B ^(q&3)
  const int qt = 31 - (int)blockIdx.x;  // longest first
  const int h = blockIdx.y, b = blockIdx.z;
  const int kvh = h >> 2;               // N_REP = 4
  const int tid = threadIdx.x, w = tid >> 6, l = tid & 63, g = l >> 4, ql = l & 15;
  const float SL2E = 0.08838834764831845f * 1.4426950408889634f;
  const u16* Qh = Qb + (size_t)b * S_ * NQ_ + h * HD_;
  const u16* Kh = Kb + ((size_t)b * S_ * KV_ + kvh) * HD_;
  const u16* Vh = VTg + (size_t)(b * KV_ + kvh) * (32 * 8192);
  u16* Oh = Ob + (size_t)b * S_ * NQ_ + h * HD_;

  bf16x8 aq[4];
  #pragma unroll
  for (int kk = 0; kk < 4; ++kk)
    aq[kk] = *(const bf16x8*)(Qh + (size_t)(qt * 64 + w * 16 + ql) * NQ_ + kk * 32 + g * 8);

  f32x4 o[8] = {};
  float mrow = -3.0e38f, lrow = 0.f;

  const int nkt = 2 * qt + 2;
  for (int kt = 0; kt < nkt; ++kt) {
    #pragma unroll
    for (int p = 0; p < 2; ++p) {   // K: [32][128]
      int c = tid + p * 256;
      int row = c >> 4, slot = c & 15;
      GLDS16(Kh + (size_t)(kt * 32 + row) * (KV_ * HD_) + ((slot ^ (row & 7)) << 3), Ks + c * 8);
    }
    #pragma unroll
    for (int p = 0; p < 2; ++p) {   // V^T: [128][32] from 16KB global tile (s-half kt&1)
      int c = tid + p * 256;
      int row = c >> 2, slot = c & 3;
      GLDS16(Vh + (size_t)(kt >> 1) * 8192 + row * 64 + (kt & 1) * 32 + ((slot ^ (row & 3)) << 3),
             Vs + c * 8);
    }
    asm volatile("s_waitcnt vmcnt(0)" ::: "memory");
    __builtin_amdgcn_s_barrier();

    if (kt * 32 <= qt * 64 + w * 16 + 15) {   // wave-uniform activity gate
      // ---- S^T = K * Q^T ----
      f32x4 sc[2] = {};
      #pragma unroll
      for (int kk = 0; kk < 4; ++kk) {
        bf16x8 bk[2];
        #pragma unroll
        for (int n = 0; n < 2; ++n) {
          int row = n * 16 + ql;
          bk[n] = *(const bf16x8*)(Ks + row * 128 + (((kk * 4 + g) ^ (row & 7)) << 3));
        }
        #pragma unroll
        for (int n = 0; n < 2; ++n)
          sc[n] = mfma16(bk[n], aq[kk], sc[n]);
      }
      // ---- causal mask (diagonal tiles only) ----
      const int qglob = qt * 64 + w * 16 + ql;
      if (kt * 32 + 31 > qt * 64 + w * 16) {
        #pragma unroll
        for (int n = 0; n < 2; ++n)
          #pragma unroll
          for (int j = 0; j < 4; ++j)
            if (kt * 32 + n * 16 + g * 4 + j > qglob) sc[n][j] = -3.0e38f;
      }
      // ---- online softmax: tree-max over 8 in-lane, then xor16/xor32 ----
      float mx = fmaxf(fmaxf(fmaxf(sc[0][0], sc[0][1]), fmaxf(sc[0][2], sc[0][3])),
                       fmaxf(fmaxf(sc[1][0], sc[1][1]), fmaxf(sc[1][2], sc[1][3])));
      mx = fmaxf(mx, __shfl_xor(mx, 16));
      mx = fmaxf(mx, __shfl_xor(mx, 32));
      if (!__all(mx - mrow <= 16.0f)) {      // defer-max: P bounded by 2^2.04
        float mnew = fmaxf(mrow, mx);
        float f = exp2f((mrow - mnew) * SL2E);
        lrow *= f;
        #pragma unroll
        for (int m = 0; m < 8; ++m) o[m] *= f;
        mrow = mnew;
      }
      float rs = 0.f;
      #pragma unroll
      for (int n = 0; n < 2; ++n)
        #pragma unroll
        for (int j = 0; j < 4; ++j) {
          float pv = exp2f((sc[n][j] - mrow) * SL2E);
          sc[n][j] = pv; rs += pv;
        }
      rs += __shfl_xor(rs, 16);
      rs += __shfl_xor(rs, 32);
      lrow += rs;
      // ---- P -> LDS: [16 q][32 k], 16B chunk ^ (q&3); 2 x u16x4 writes ----
      u16* Pw = Ps + w * 512;
      #pragma unroll
      for (int n = 0; n < 2; ++n) {
        u16x4 pk;
        #pragma unroll
        for (int j = 0; j < 4; ++j) pk[j] = f2bft(sc[n][j]);
        *(u16x4*)(Pw + ql * 32 + (((n * 2 + (g >> 1)) ^ (ql & 3)) << 3) + (g & 1) * 4) = pk;
      }
      // ---- PV: O^T = V^T * P^T (single 32-k slab) ----
      bf16x8 bp = *(const bf16x8*)(Pw + ql * 32 + ((g ^ (ql & 3)) << 3));
      #pragma unroll
      for (int m = 0; m < 8; ++m) {
        int row = m * 16 + ql;
        bf16x8 av = *(const bf16x8*)(Vs + row * 32 + ((g ^ (row & 3)) << 3));
        o[m] = mfma16(av, bp, o[m]);
      }
    }
    __builtin_amdgcn_s_barrier();   // all waves done with Ks/Vs before restage
  }
  // ---- epilogue: normalize (lane-local), transpose via LDS, store ----
  __syncthreads();
  u16* OS = SM; // [64][136]
  float linv = 1.0f / lrow;
  #pragma unroll
  for (int m = 0; m < 8; ++m)
    #pragma unroll
    for (int j = 0; j < 4; ++j)
      OS[(w * 16 + ql) * 136 + m * 16 + g * 4 + j] = f2bf(o[m][j] * linv);
  __syncthreads();
  #pragma unroll
  for (int p = 0; p < 4; ++p) {
    int c = tid + p * 256;
    int row = c >> 4, col8 = c & 15;
    u16x8 d = *(const u16x8*)(OS + row * 136 + col8 * 8);
    *(u16x8*)(Oh + (size_t)(qt * 64 + row) * NQ_ + col8 * 8) = d;
  }
}

extern "C" void kernel_launch(void* const* d_in, const int* in_sizes, int n_in,
                              void* d_out, int out_size, void* d_ws, size_t ws_size,
                              hipStream_t stream) {
  const float* x  = (const float*)d_in[0];
  const float* fc = (const float*)d_in[1];
  const float* fs = (const float*)d_in[2];
  // d_in[3] = mask (causal, applied analytically)
  const float* wq = (const float*)d_in[4];
  const float* wk = (const float*)d_in[5];
  const float* wv = (const float*)d_in[6];
  const float* wo = (const float*)d_in[7];

  char* ws = (char*)d_ws;
  u16* xb  = (u16*)(ws + 0);          // 33554432 B
  u16* wqT = (u16*)(ws + 33554432);   // 33554432
  u16* wkT = (u16*)(ws + 67108864);   // 8388608   (wkT||wvT = [2048][4096])
  u16* wvT = (u16*)(ws + 75497472);   // 8388608
  u16* woT = (u16*)(ws + 83886080);   // 33554432
  u16* qb  = (u16*)(ws + 117440512);  // 33554432
  u16* kb  = (u16*)(ws + 150994944);  // 8388608
  u16* vtg = (u16*)(ws + 159383552);  // 8388608  (V^T tiled: [B][KV][32][128][64])
  u16* ob  = (u16*)(ws + 167772160);  // 33554432  -> total 201326592
  if (ws_size < 201326592u) return;

  cvt_bf16<<<(M_ * D_) / (8 * 256), 256, 0, stream>>>(x, xb, M_ * D_);
  tcvt<<<dim3(NQ_ / 64, D_ / 64), 256, 0, stream>>>(wq, wqT, D_, NQ_);
  tcvt<<<dim3(NKV_ / 64, D_ / 64), 256, 0, stream>>>(wk, wkT, D_, NKV_);
  tcvt<<<dim3(NKV_ / 64, D_ / 64), 256, 0, stream>>>(wv, wvT, D_, NKV_);
  tcvt<<<dim3(D_ / 64, NQ_ / 64), 256, 0, stream>>>(wo, woT, NQ_, D_);

  gemm256<0><<<(NQ_ / 256) * (M_ / 256), 512, 98304, stream>>>(xb, wqT, qb, M_, NQ_, D_);
  // fused K+V projection: N=2048 (wkT||wvT contiguous), 256x128-tile pipeline
  gemm_kv<<<(2048 / 128) * (M_ / 256), 512, 73728, stream>>>(xb, wkT, kb, vtg, M_, 2048, D_);

  rope_kernel<<<(M_ * NQ_ / 2) / 256, 256, 0, stream>>>(qb, fc, fs, 11, M_ * NQ_ / 2);
  rope_kernel<<<(M_ * NKV_ / 2) / 256, 256, 0, stream>>>(kb, fc, fs, 9, M_ * NKV_ / 2);

  attn_kernel<<<dim3(32, H_, B_), 256, 0, stream>>>(qb, kb, vtg, ob);

  gemm256<1><<<(D_ / 256) * (M_ / 256), 512, 98304, stream>>>(ob, woT, d_out, M_, D_, NQ_);
}

// Round 13
// 617.668 us; speedup vs baseline: 1.7696x; 1.7696x over previous
//
#include <hip/hip_runtime.h>
#include <stdint.h>

#define B_ 2
#define S_ 2048
#define D_ 4096
#define H_ 32
#define KV_ 8
#define HD_ 128
#define M_ (B_*S_)          // 4096 rows (b*S+s)
#define NQ_ (H_*HD_)        // 4096
#define NKV_ (KV_*HD_)      // 1024

typedef unsigned short u16;
typedef __bf16 bf16x8 __attribute__((ext_vector_type(8)));
typedef float f32x4 __attribute__((ext_vector_type(4)));
typedef u16 u16x8 __attribute__((ext_vector_type(8)));
typedef u16 u16x4 __attribute__((ext_vector_type(4)));

__device__ __forceinline__ u16 f2bf(float f) {
  union { float f; unsigned u; } v; v.f = f;
  unsigned r = v.u + 0x7fffu + ((v.u >> 16) & 1u);
  return (u16)(r >> 16);
}
__device__ __forceinline__ u16 f2bft(float f) {  // truncating (for P; values in [0,4.2])
  union { float f; unsigned u; } v; v.f = f;
  return (u16)(v.u >> 16);
}
__device__ __forceinline__ float bf2f(u16 u) {
  union { unsigned u; float f; } v; v.u = ((unsigned)u) << 16;
  return v.f;
}
__device__ __forceinline__ f32x4 mfma16(bf16x8 a, bf16x8 b, f32x4 c) {
  return __builtin_amdgcn_mfma_f32_16x16x32_bf16(a, b, c, 0, 0, 0);
}

#define GLDS16(gp, lp) __builtin_amdgcn_global_load_lds( \
    (const __attribute__((address_space(1))) unsigned int*)(gp), \
    (__attribute__((address_space(3))) unsigned int*)(lp), 16, 0, 0)

// ---------------- fp32 -> bf16 convert (vectorized) ----------------
__global__ __launch_bounds__(256) void cvt_bf16(const float* __restrict__ in,
                                                u16* __restrict__ out, int n) {
  int i = (blockIdx.x * 256 + threadIdx.x) * 8;
  if (i >= n) return;
  float4 a = *(const float4*)(in + i);
  float4 b = *(const float4*)(in + i + 4);
  u16x8 o;
  o[0]=f2bf(a.x); o[1]=f2bf(a.y); o[2]=f2bf(a.z); o[3]=f2bf(a.w);
  o[4]=f2bf(b.x); o[5]=f2bf(b.y); o[6]=f2bf(b.z); o[7]=f2bf(b.w);
  *(u16x8*)(out + i) = o;
}

// -------- transpose + convert: out[c][r] = in[r][c], 64x64, vectorized --------
__global__ __launch_bounds__(256) void tcvt(const float* __restrict__ in,
                                            u16* __restrict__ out, int R, int C) {
  __shared__ float tf[64][65];
  int c0 = blockIdx.x * 64, r0 = blockIdx.y * 64;
  int l16 = threadIdx.x & 15, r16 = threadIdx.x >> 4;
  #pragma unroll
  for (int p = 0; p < 4; ++p) {
    int r = p * 16 + r16;
    float4 v = *(const float4*)(in + (size_t)(r0 + r) * C + c0 + l16 * 4);
    tf[r][l16 * 4 + 0] = v.x; tf[r][l16 * 4 + 1] = v.y;
    tf[r][l16 * 4 + 2] = v.z; tf[r][l16 * 4 + 3] = v.w;
  }
  __syncthreads();
  int oc = threadIdx.x >> 2, ch = threadIdx.x & 3;
  u16x8 o1, o2;
  #pragma unroll
  for (int i = 0; i < 8; ++i) o1[i] = f2bf(tf[ch * 16 + i][oc]);
  #pragma unroll
  for (int i = 0; i < 8; ++i) o2[i] = f2bf(tf[ch * 16 + 8 + i][oc]);
  *(u16x8*)(out + (size_t)(c0 + oc) * R + r0 + ch * 16) = o1;
  *(u16x8*)(out + (size_t)(c0 + oc) * R + r0 + ch * 16 + 8) = o2;
}

// ------- 256x256 GEMM, 3-buf rotation + FULL cross-tile register pipeline -------
// (unchanged from R10; ~1015 TF, sync-economics-capped at this geometry.)
template<int OUTMODE>
__global__ __launch_bounds__(512, 2) void gemm256(const u16* __restrict__ A,
    const u16* __restrict__ BT, void* __restrict__ Cv, int M, int N, int K) {
  extern __shared__ __attribute__((aligned(16))) u16 DL[];  // 3 x 16384 u16
  const int tid = threadIdx.x;
  const int nbx = N >> 8;
  const int cpx = gridDim.x >> 3;                 // grid % 8 == 0
  const int swzb = (blockIdx.x & 7) * cpx + (blockIdx.x >> 3);
  const int bn0 = (swzb % nbx) << 8, bm0 = (swzb / nbx) << 8;
  const int l = tid & 63, g = l >> 4, q = l & 15;
  const int w = tid >> 6;
  const int wm = (w >> 2) * 128, wn = (w & 3) * 64;
  const int nt = K >> 5;   // BK = 32
  f32x4 acc[8][4] = {};

  const int srow = tid >> 2, schunk = tid & 3;
  const int ssw = (schunk ^ ((srow >> 1) & 3)) << 3;
  const u16* gA0 = A  + (size_t)(bm0 + srow) * K + ssw;
  const u16* gA1 = gA0 + (size_t)128 * K;
  const u16* gB0 = BT + (size_t)(bn0 + srow) * K + ssw;
  const u16* gB1 = gB0 + (size_t)128 * K;

  auto STAGE = [&](int t) {
    const int kt = t << 5;
    u16* d = DL + (t % 3) * 16384;
    GLDS16(gA0 + kt, d + tid * 8);
    GLDS16(gA1 + kt, d + 4096 + tid * 8);
    GLDS16(gB0 + kt, d + 8192 + tid * 8);
    GLDS16(gB1 + kt, d + 12288 + tid * 8);
  };

  const u16* ra = DL + (wm + q) * 32 + ((g ^ (((wm + q) >> 1) & 3)) << 3);
  const u16* rb = DL + 8192 + (wn + q) * 32 + ((g ^ (((wn + q) >> 1) & 3)) << 3);

  bf16x8 aC[8], aN[8], bC[4], bN[4];

  STAGE(0); STAGE(1);
  asm volatile("s_waitcnt vmcnt(4)" ::: "memory");
  __builtin_amdgcn_s_barrier();
  #pragma unroll
  for (int m = 0; m < 8; ++m) aC[m] = *(const bf16x8*)(ra + m * 512);
  #pragma unroll
  for (int n = 0; n < 4; ++n) bC[n] = *(const bf16x8*)(rb + n * 512);

  auto TILE = [&](int t, bf16x8 (&ac)[8], bf16x8 (&bc)[4],
                         bf16x8 (&an)[8], bf16x8 (&bn)[4]) {
    if (t + 2 < nt) {
      STAGE(t + 2);
      asm volatile("s_waitcnt vmcnt(4)" ::: "memory");
    } else {
      asm volatile("s_waitcnt vmcnt(0)" ::: "memory");
    }
    __builtin_amdgcn_s_barrier();
    if (t + 1 < nt) {
      const u16* pa = ra + ((t + 1) % 3) * 16384;
      const u16* pb = rb + ((t + 1) % 3) * 16384;
      #pragma unroll
      for (int m = 0; m < 8; ++m) an[m] = *(const bf16x8*)(pa + m * 512);
      #pragma unroll
      for (int n = 0; n < 4; ++n) bn[n] = *(const bf16x8*)(pb + n * 512);
    }
    __builtin_amdgcn_s_setprio(1);
    #pragma unroll
    for (int m = 0; m < 8; ++m) {
      acc[m][0] = mfma16(ac[m], bc[0], acc[m][0]);
      acc[m][1] = mfma16(ac[m], bc[1], acc[m][1]);
      acc[m][2] = mfma16(ac[m], bc[2], acc[m][2]);
      acc[m][3] = mfma16(ac[m], bc[3], acc[m][3]);
    }
    __builtin_amdgcn_s_setprio(0);
  };

  for (int t = 0; t < nt; t += 2) {
    TILE(t,     aC, bC, aN, bN);
    TILE(t + 1, aN, bN, aC, bC);
  }

  #pragma unroll
  for (int m = 0; m < 8; ++m)
    #pragma unroll
    for (int n = 0; n < 4; ++n)
      #pragma unroll
      for (int j = 0; j < 4; ++j) {
        size_t off = (size_t)(bm0 + wm + m * 16 + g * 4 + j) * N + (bn0 + wn + n * 16 + q);
        if (OUTMODE == 1) ((float*)Cv)[off] = acc[m][n][j];
        else              ((u16*)Cv)[off]  = f2bf(acc[m][n][j]);
      }
}

// ------- KV projection GEMM: BM=256 x BN=128, same 3-buf reg pipeline -------
__global__ __launch_bounds__(512, 2) void gemm_kv(const u16* __restrict__ A,
    const u16* __restrict__ BT, u16* __restrict__ Ck, u16* __restrict__ Cvt,
    int M, int N, int K) {
  extern __shared__ __attribute__((aligned(16))) u16 DL[];  // 3 x 12288 u16
  const int tid = threadIdx.x;
  const int nbx = N >> 7;                          // 16
  const int cpx = gridDim.x >> 3;
  const int swzb = (blockIdx.x & 7) * cpx + (blockIdx.x >> 3);
  const int bn0 = (swzb % nbx) << 7, bm0 = (swzb / nbx) << 8;
  const int l = tid & 63, g = l >> 4, q = l & 15;
  const int w = tid >> 6;
  const int wm = (w >> 2) * 128, wn = (w & 3) * 32;
  const int nt = K >> 5;
  f32x4 acc[8][2] = {};

  const int srow = tid >> 2, schunk = tid & 3;
  const int ssw = (schunk ^ ((srow >> 1) & 3)) << 3;
  const u16* gA0 = A  + (size_t)(bm0 + srow) * K + ssw;
  const u16* gA1 = gA0 + (size_t)128 * K;
  const u16* gB0 = BT + (size_t)(bn0 + srow) * K + ssw;

  auto STAGE = [&](int t) {
    const int kt = t << 5;
    u16* d = DL + (t % 3) * 12288;
    GLDS16(gA0 + kt, d + tid * 8);
    GLDS16(gA1 + kt, d + 4096 + tid * 8);
    GLDS16(gB0 + kt, d + 8192 + tid * 8);
  };

  const u16* ra = DL + (wm + q) * 32 + ((g ^ (((wm + q) >> 1) & 3)) << 3);
  const u16* rb = DL + 8192 + (wn + q) * 32 + ((g ^ (((wn + q) >> 1) & 3)) << 3);

  bf16x8 aC[8], aN[8], bC[2], bN[2];

  STAGE(0); STAGE(1);
  asm volatile("s_waitcnt vmcnt(3)" ::: "memory");
  __builtin_amdgcn_s_barrier();
  #pragma unroll
  for (int m = 0; m < 8; ++m) aC[m] = *(const bf16x8*)(ra + m * 512);
  #pragma unroll
  for (int n = 0; n < 2; ++n) bC[n] = *(const bf16x8*)(rb + n * 512);

  auto TILE = [&](int t, bf16x8 (&ac)[8], bf16x8 (&bc)[2],
                         bf16x8 (&an)[8], bf16x8 (&bn)[2]) {
    if (t + 2 < nt) {
      STAGE(t + 2);
      asm volatile("s_waitcnt vmcnt(3)" ::: "memory");
    } else {
      asm volatile("s_waitcnt vmcnt(0)" ::: "memory");
    }
    __builtin_amdgcn_s_barrier();
    if (t + 1 < nt) {
      const u16* pa = ra + ((t + 1) % 3) * 12288;
      const u16* pb = rb + ((t + 1) % 3) * 12288;
      #pragma unroll
      for (int m = 0; m < 8; ++m) an[m] = *(const bf16x8*)(pa + m * 512);
      #pragma unroll
      for (int n = 0; n < 2; ++n) bn[n] = *(const bf16x8*)(pb + n * 512);
    }
    __builtin_amdgcn_s_setprio(1);
    #pragma unroll
    for (int m = 0; m < 8; ++m) {
      acc[m][0] = mfma16(ac[m], bc[0], acc[m][0]);
      acc[m][1] = mfma16(ac[m], bc[1], acc[m][1]);
    }
    __builtin_amdgcn_s_setprio(0);
  };

  for (int t = 0; t < nt; t += 2) {
    TILE(t,     aC, bC, aN, bN);
    TILE(t + 1, aN, bN, aC, bC);
  }

  #pragma unroll
  for (int m = 0; m < 8; ++m)
    #pragma unroll
    for (int n = 0; n < 2; ++n) {
      int row0 = bm0 + wm + m * 16 + g * 4;
      int col  = bn0 + wn + n * 16 + q;
      if (col < 1024) {
        #pragma unroll
        for (int j = 0; j < 4; ++j)
          Ck[(size_t)(row0 + j) * 1024 + col] = f2bf(acc[m][n][j]);
      } else {
        int c2 = col - 1024;
        u16x4 pk;
        #pragma unroll
        for (int j = 0; j < 4; ++j) pk[j] = f2bf(acc[m][n][j]);
        size_t off = ((size_t)((row0 >> 11) * KV_ + (c2 >> 7)) * 32 + ((row0 >> 6) & 31)) * 8192
                   + (size_t)(c2 & 127) * 64 + (row0 & 63);
        *(u16x4*)(Cvt + off) = pk;
      }
    }
}

// ---------------- RoPE (interleaved pairs, in-place on bf16) ----------------
__global__ __launch_bounds__(256) void rope_kernel(u16* __restrict__ t,
    const float* __restrict__ fc, const float* __restrict__ fs,
    int log2ppr, int total_pairs) {
  int i = blockIdx.x * 256 + threadIdx.x;
  if (i >= total_pairs) return;
  int fi = i & 63;
  int row = i >> log2ppr;           // b*S + s
  int pos = row & (S_ - 1);
  float c = fc[pos * 64 + fi], s = fs[pos * 64 + fi];
  unsigned* p = (unsigned*)(t + 2 * (size_t)i);
  unsigned v = *p;
  float x0 = bf2f((u16)(v & 0xffffu)), x1 = bf2f((u16)(v >> 16));
  float r0 = x0 * c - x1 * s, r1 = x0 * s + x1 * c;
  *p = (unsigned)f2bf(r0) | ((unsigned)f2bf(r1) << 16);
}

// ---------------- causal GQA flash attention (swapped-QK^T, KT=32) ----------------
// Occupancy thesis (R12): grid (32,H,B)=2048 blocks, LDS 20KB -> 8 blocks/CU.
// R12 BUG: launch_bounds(256,8) capped VGPR at 512/8=32 -> spill (FETCH 1GB).
// Fixed: (256,4) -> cap 128; kernel compiles ~64 VGPR naturally (R11 measured
// 64), so HW still schedules 8 waves/SIMD. NEVER set arg2 > 512/measured_VGPR.
// Swizzle fix: 32-wide tiles (V^T,P) use s(row)=(row>>1)&3 -- old (row&3)
// aliased rows {0,4,8,12} onto one bank quad (4-way); new = exactly 2-way (free).
__global__ __launch_bounds__(256, 4) void attn_kernel(
    const u16* __restrict__ Qb, const u16* __restrict__ Kb,
    const u16* __restrict__ VTg, u16* __restrict__ Ob) {
  __shared__ __attribute__((aligned(16))) u16 SM[10240]; // 20KB
  u16* Ks = SM;            // [32][128] swz chunk16B ^(row&7)
  u16* Vs = SM + 4096;     // [128][32] swz chunk16B ^((row>>1)&3)
  u16* Ps = SM + 8192;     // 4 waves x [16 q][32 k], chunk16B ^((q>>1)&3)
  const int qt = 31 - (int)blockIdx.x;  // longest first
  const int h = blockIdx.y, b = blockIdx.z;
  const int kvh = h >> 2;               // N_REP = 4
  const int tid = threadIdx.x, w = tid >> 6, l = tid & 63, g = l >> 4, ql = l & 15;
  const float SL2E = 0.08838834764831845f * 1.4426950408889634f;
  const u16* Qh = Qb + (size_t)b * S_ * NQ_ + h * HD_;
  const u16* Kh = Kb + ((size_t)b * S_ * KV_ + kvh) * HD_;
  const u16* Vh = VTg + (size_t)(b * KV_ + kvh) * (32 * 8192);
  u16* Oh = Ob + (size_t)b * S_ * NQ_ + h * HD_;

  bf16x8 aq[4];
  #pragma unroll
  for (int kk = 0; kk < 4; ++kk)
    aq[kk] = *(const bf16x8*)(Qh + (size_t)(qt * 64 + w * 16 + ql) * NQ_ + kk * 32 + g * 8);

  f32x4 o[8] = {};
  float mrow = -3.0e38f, lrow = 0.f;

  const int nkt = 2 * qt + 2;
  for (int kt = 0; kt < nkt; ++kt) {
    #pragma unroll
    for (int p = 0; p < 2; ++p) {   // K: [32][128]
      int c = tid + p * 256;
      int row = c >> 4, slot = c & 15;
      GLDS16(Kh + (size_t)(kt * 32 + row) * (KV_ * HD_) + ((slot ^ (row & 7)) << 3), Ks + c * 8);
    }
    #pragma unroll
    for (int p = 0; p < 2; ++p) {   // V^T: [128][32] from 16KB global tile (s-half kt&1)
      int c = tid + p * 256;
      int row = c >> 2, slot = c & 3;
      GLDS16(Vh + (size_t)(kt >> 1) * 8192 + row * 64 + (kt & 1) * 32 + ((slot ^ ((row >> 1) & 3)) << 3),
             Vs + c * 8);
    }
    asm volatile("s_waitcnt vmcnt(0)" ::: "memory");
    __builtin_amdgcn_s_barrier();

    if (kt * 32 <= qt * 64 + w * 16 + 15) {   // wave-uniform activity gate
      // ---- S^T = K * Q^T ----
      f32x4 sc[2] = {};
      #pragma unroll
      for (int kk = 0; kk < 4; ++kk) {
        bf16x8 bk[2];
        #pragma unroll
        for (int n = 0; n < 2; ++n) {
          int row = n * 16 + ql;
          bk[n] = *(const bf16x8*)(Ks + row * 128 + (((kk * 4 + g) ^ (row & 7)) << 3));
        }
        #pragma unroll
        for (int n = 0; n < 2; ++n)
          sc[n] = mfma16(bk[n], aq[kk], sc[n]);
      }
      // ---- causal mask (diagonal tiles only) ----
      const int qglob = qt * 64 + w * 16 + ql;
      if (kt * 32 + 31 > qt * 64 + w * 16) {
        #pragma unroll
        for (int n = 0; n < 2; ++n)
          #pragma unroll
          for (int j = 0; j < 4; ++j)
            if (kt * 32 + n * 16 + g * 4 + j > qglob) sc[n][j] = -3.0e38f;
      }
      // ---- online softmax: tree-max over 8 in-lane, then xor16/xor32 ----
      float mx = fmaxf(fmaxf(fmaxf(sc[0][0], sc[0][1]), fmaxf(sc[0][2], sc[0][3])),
                       fmaxf(fmaxf(sc[1][0], sc[1][1]), fmaxf(sc[1][2], sc[1][3])));
      mx = fmaxf(mx, __shfl_xor(mx, 16));
      mx = fmaxf(mx, __shfl_xor(mx, 32));
      if (!__all(mx - mrow <= 16.0f)) {      // defer-max: P bounded by 2^2.04
        float mnew = fmaxf(mrow, mx);
        float f = exp2f((mrow - mnew) * SL2E);
        lrow *= f;
        #pragma unroll
        for (int m = 0; m < 8; ++m) o[m] *= f;
        mrow = mnew;
      }
      float rs = 0.f;
      #pragma unroll
      for (int n = 0; n < 2; ++n)
        #pragma unroll
        for (int j = 0; j < 4; ++j) {
          float pv = exp2f((sc[n][j] - mrow) * SL2E);
          sc[n][j] = pv; rs += pv;
        }
      rs += __shfl_xor(rs, 16);
      rs += __shfl_xor(rs, 32);
      lrow += rs;
      // ---- P -> LDS: [16 q][32 k], 16B chunk ^ ((q>>1)&3); 2 x u16x4 writes ----
      u16* Pw = Ps + w * 512;
      #pragma unroll
      for (int n = 0; n < 2; ++n) {
        u16x4 pk;
        #pragma unroll
        for (int j = 0; j < 4; ++j) pk[j] = f2bft(sc[n][j]);
        *(u16x4*)(Pw + ql * 32 + (((n * 2 + (g >> 1)) ^ ((ql >> 1) & 3)) << 3) + (g & 1) * 4) = pk;
      }
      // ---- PV: O^T = V^T * P^T (single 32-k slab) ----
      bf16x8 bp = *(const bf16x8*)(Pw + ql * 32 + ((g ^ ((ql >> 1) & 3)) << 3));
      #pragma unroll
      for (int m = 0; m < 8; ++m) {
        int row = m * 16 + ql;
        bf16x8 av = *(const bf16x8*)(Vs + row * 32 + ((g ^ ((row >> 1) & 3)) << 3));
        o[m] = mfma16(av, bp, o[m]);
      }
    }
    __builtin_amdgcn_s_barrier();   // all waves done with Ks/Vs before restage
  }
  // ---- epilogue: normalize (lane-local), transpose via LDS, store ----
  __syncthreads();
  u16* OS = SM; // [64][136]
  float linv = 1.0f / lrow;
  #pragma unroll
  for (int m = 0; m < 8; ++m)
    #pragma unroll
    for (int j = 0; j < 4; ++j)
      OS[(w * 16 + ql) * 136 + m * 16 + g * 4 + j] = f2bf(o[m][j] * linv);
  __syncthreads();
  #pragma unroll
  for (int p = 0; p < 4; ++p) {
    int c = tid + p * 256;
    int row = c >> 4, col8 = c & 15;
    u16x8 d = *(const u16x8*)(OS + row * 136 + col8 * 8);
    *(u16x8*)(Oh + (size_t)(qt * 64 + row) * NQ_ + col8 * 8) = d;
  }
}

extern "C" void kernel_launch(void* const* d_in, const int* in_sizes, int n_in,
                              void* d_out, int out_size, void* d_ws, size_t ws_size,
                              hipStream_t stream) {
  const float* x  = (const float*)d_in[0];
  const float* fc = (const float*)d_in[1];
  const float* fs = (const float*)d_in[2];
  // d_in[3] = mask (causal, applied analytically)
  const float* wq = (const float*)d_in[4];
  const float* wk = (const float*)d_in[5];
  const float* wv = (const float*)d_in[6];
  const float* wo = (const float*)d_in[7];

  char* ws = (char*)d_ws;
  u16* xb  = (u16*)(ws + 0);          // 33554432 B
  u16* wqT = (u16*)(ws + 33554432);   // 33554432
  u16* wkT = (u16*)(ws + 67108864);   // 8388608   (wkT||wvT = [2048][4096])
  u16* wvT = (u16*)(ws + 75497472);   // 8388608
  u16* woT = (u16*)(ws + 83886080);   // 33554432
  u16* qb  = (u16*)(ws + 117440512);  // 33554432
  u16* kb  = (u16*)(ws + 150994944);  // 8388608
  u16* vtg = (u16*)(ws + 159383552);  // 8388608  (V^T tiled: [B][KV][32][128][64])
  u16* ob  = (u16*)(ws + 167772160);  // 33554432  -> total 201326592
  if (ws_size < 201326592u) return;

  cvt_bf16<<<(M_ * D_) / (8 * 256), 256, 0, stream>>>(x, xb, M_ * D_);
  tcvt<<<dim3(NQ_ / 64, D_ / 64), 256, 0, stream>>>(wq, wqT, D_, NQ_);
  tcvt<<<dim3(NKV_ / 64, D_ / 64), 256, 0, stream>>>(wk, wkT, D_, NKV_);
  tcvt<<<dim3(NKV_ / 64, D_ / 64), 256, 0, stream>>>(wv, wvT, D_, NKV_);
  tcvt<<<dim3(D_ / 64, NQ_ / 64), 256, 0, stream>>>(wo, woT, NQ_, D_);

  gemm256<0><<<(NQ_ / 256) * (M_ / 256), 512, 98304, stream>>>(xb, wqT, qb, M_, NQ_, D_);
  // fused K+V projection: N=2048 (wkT||wvT contiguous), 256x128-tile pipeline
  gemm_kv<<<(2048 / 128) * (M_ / 256), 512, 73728, stream>>>(xb, wkT, kb, vtg, M_, 2048, D_);

  rope_kernel<<<(M_ * NQ_ / 2) / 256, 256, 0, stream>>>(qb, fc, fs, 11, M_ * NQ_ / 2);
  rope_kernel<<<(M_ * NKV_ / 2) / 256, 256, 0, stream>>>(kb, fc, fs, 9, M_ * NKV_ / 2);

  attn_kernel<<<dim3(32, H_, B_), 256, 0, stream>>>(qb, kb, vtg, ob);

  gemm256<1><<<(D_ / 256) * (M_ / 256), 512, 98304, stream>>>(ob, woT, d_out, M_, D_, NQ_);
}

// Round 14
// 526.541 us; speedup vs baseline: 2.0759x; 1.1731x over previous
//
#include <hip/hip_runtime.h>
#include <stdint.h>

#define B_ 2
#define S_ 2048
#define D_ 4096
#define H_ 32
#define KV_ 8
#define HD_ 128
#define M_ (B_*S_)          // 4096 rows (b*S+s)
#define NQ_ (H_*HD_)        // 4096
#define NKV_ (KV_*HD_)      // 1024

typedef unsigned short u16;
typedef __bf16 bf16x8 __attribute__((ext_vector_type(8)));
typedef float f32x4 __attribute__((ext_vector_type(4)));
typedef u16 u16x8 __attribute__((ext_vector_type(8)));
typedef u16 u16x4 __attribute__((ext_vector_type(4)));

__device__ __forceinline__ u16 f2bf(float f) {
  union { float f; unsigned u; } v; v.f = f;
  unsigned r = v.u + 0x7fffu + ((v.u >> 16) & 1u);
  return (u16)(r >> 16);
}
__device__ __forceinline__ u16 f2bft(float f) {  // truncating (for P; values in [0,4.2])
  union { float f; unsigned u; } v; v.f = f;
  return (u16)(v.u >> 16);
}
__device__ __forceinline__ float bf2f(u16 u) {
  union { unsigned u; float f; } v; v.u = ((unsigned)u) << 16;
  return v.f;
}
__device__ __forceinline__ f32x4 mfma16(bf16x8 a, bf16x8 b, f32x4 c) {
  return __builtin_amdgcn_mfma_f32_16x16x32_bf16(a, b, c, 0, 0, 0);
}

#define GLDS16(gp, lp) __builtin_amdgcn_global_load_lds( \
    (const __attribute__((address_space(1))) unsigned int*)(gp), \
    (__attribute__((address_space(3))) unsigned int*)(lp), 16, 0, 0)

// ---------------- fp32 -> bf16 convert (vectorized) ----------------
__global__ __launch_bounds__(256) void cvt_bf16(const float* __restrict__ in,
                                                u16* __restrict__ out, int n) {
  int i = (blockIdx.x * 256 + threadIdx.x) * 8;
  if (i >= n) return;
  float4 a = *(const float4*)(in + i);
  float4 b = *(const float4*)(in + i + 4);
  u16x8 o;
  o[0]=f2bf(a.x); o[1]=f2bf(a.y); o[2]=f2bf(a.z); o[3]=f2bf(a.w);
  o[4]=f2bf(b.x); o[5]=f2bf(b.y); o[6]=f2bf(b.z); o[7]=f2bf(b.w);
  *(u16x8*)(out + i) = o;
}

// -------- transpose + convert: out[c][r] = in[r][c], 64x64, vectorized --------
__global__ __launch_bounds__(256) void tcvt(const float* __restrict__ in,
                                            u16* __restrict__ out, int R, int C) {
  __shared__ float tf[64][65];
  int c0 = blockIdx.x * 64, r0 = blockIdx.y * 64;
  int l16 = threadIdx.x & 15, r16 = threadIdx.x >> 4;
  #pragma unroll
  for (int p = 0; p < 4; ++p) {
    int r = p * 16 + r16;
    float4 v = *(const float4*)(in + (size_t)(r0 + r) * C + c0 + l16 * 4);
    tf[r][l16 * 4 + 0] = v.x; tf[r][l16 * 4 + 1] = v.y;
    tf[r][l16 * 4 + 2] = v.z; tf[r][l16 * 4 + 3] = v.w;
  }
  __syncthreads();
  int oc = threadIdx.x >> 2, ch = threadIdx.x & 3;
  u16x8 o1, o2;
  #pragma unroll
  for (int i = 0; i < 8; ++i) o1[i] = f2bf(tf[ch * 16 + i][oc]);
  #pragma unroll
  for (int i = 0; i < 8; ++i) o2[i] = f2bf(tf[ch * 16 + 8 + i][oc]);
  *(u16x8*)(out + (size_t)(c0 + oc) * R + r0 + ch * 16) = o1;
  *(u16x8*)(out + (size_t)(c0 + oc) * R + r0 + ch * 16 + 8) = o2;
}

// ------- 256x256 GEMM, 3-buf rotation + FULL cross-tile register pipeline -------
// (unchanged from R10; ~1015 TF, sync-economics-capped at this geometry.)
template<int OUTMODE>
__global__ __launch_bounds__(512, 2) void gemm256(const u16* __restrict__ A,
    const u16* __restrict__ BT, void* __restrict__ Cv, int M, int N, int K) {
  extern __shared__ __attribute__((aligned(16))) u16 DL[];  // 3 x 16384 u16
  const int tid = threadIdx.x;
  const int nbx = N >> 8;
  const int cpx = gridDim.x >> 3;                 // grid % 8 == 0
  const int swzb = (blockIdx.x & 7) * cpx + (blockIdx.x >> 3);
  const int bn0 = (swzb % nbx) << 8, bm0 = (swzb / nbx) << 8;
  const int l = tid & 63, g = l >> 4, q = l & 15;
  const int w = tid >> 6;
  const int wm = (w >> 2) * 128, wn = (w & 3) * 64;
  const int nt = K >> 5;   // BK = 32
  f32x4 acc[8][4] = {};

  const int srow = tid >> 2, schunk = tid & 3;
  const int ssw = (schunk ^ ((srow >> 1) & 3)) << 3;
  const u16* gA0 = A  + (size_t)(bm0 + srow) * K + ssw;
  const u16* gA1 = gA0 + (size_t)128 * K;
  const u16* gB0 = BT + (size_t)(bn0 + srow) * K + ssw;
  const u16* gB1 = gB0 + (size_t)128 * K;

  auto STAGE = [&](int t) {
    const int kt = t << 5;
    u16* d = DL + (t % 3) * 16384;
    GLDS16(gA0 + kt, d + tid * 8);
    GLDS16(gA1 + kt, d + 4096 + tid * 8);
    GLDS16(gB0 + kt, d + 8192 + tid * 8);
    GLDS16(gB1 + kt, d + 12288 + tid * 8);
  };

  const u16* ra = DL + (wm + q) * 32 + ((g ^ (((wm + q) >> 1) & 3)) << 3);
  const u16* rb = DL + 8192 + (wn + q) * 32 + ((g ^ (((wn + q) >> 1) & 3)) << 3);

  bf16x8 aC[8], aN[8], bC[4], bN[4];

  STAGE(0); STAGE(1);
  asm volatile("s_waitcnt vmcnt(4)" ::: "memory");
  __builtin_amdgcn_s_barrier();
  #pragma unroll
  for (int m = 0; m < 8; ++m) aC[m] = *(const bf16x8*)(ra + m * 512);
  #pragma unroll
  for (int n = 0; n < 4; ++n) bC[n] = *(const bf16x8*)(rb + n * 512);

  auto TILE = [&](int t, bf16x8 (&ac)[8], bf16x8 (&bc)[4],
                         bf16x8 (&an)[8], bf16x8 (&bn)[4]) {
    if (t + 2 < nt) {
      STAGE(t + 2);
      asm volatile("s_waitcnt vmcnt(4)" ::: "memory");
    } else {
      asm volatile("s_waitcnt vmcnt(0)" ::: "memory");
    }
    __builtin_amdgcn_s_barrier();
    if (t + 1 < nt) {
      const u16* pa = ra + ((t + 1) % 3) * 16384;
      const u16* pb = rb + ((t + 1) % 3) * 16384;
      #pragma unroll
      for (int m = 0; m < 8; ++m) an[m] = *(const bf16x8*)(pa + m * 512);
      #pragma unroll
      for (int n = 0; n < 4; ++n) bn[n] = *(const bf16x8*)(pb + n * 512);
    }
    __builtin_amdgcn_s_setprio(1);
    #pragma unroll
    for (int m = 0; m < 8; ++m) {
      acc[m][0] = mfma16(ac[m], bc[0], acc[m][0]);
      acc[m][1] = mfma16(ac[m], bc[1], acc[m][1]);
      acc[m][2] = mfma16(ac[m], bc[2], acc[m][2]);
      acc[m][3] = mfma16(ac[m], bc[3], acc[m][3]);
    }
    __builtin_amdgcn_s_setprio(0);
  };

  for (int t = 0; t < nt; t += 2) {
    TILE(t,     aC, bC, aN, bN);
    TILE(t + 1, aN, bN, aC, bC);
  }

  #pragma unroll
  for (int m = 0; m < 8; ++m)
    #pragma unroll
    for (int n = 0; n < 4; ++n)
      #pragma unroll
      for (int j = 0; j < 4; ++j) {
        size_t off = (size_t)(bm0 + wm + m * 16 + g * 4 + j) * N + (bn0 + wn + n * 16 + q);
        if (OUTMODE == 1) ((float*)Cv)[off] = acc[m][n][j];
        else              ((u16*)Cv)[off]  = f2bf(acc[m][n][j]);
      }
}

// ------- KV projection GEMM: BM=256 x BN=128, same 3-buf reg pipeline -------
__global__ __launch_bounds__(512, 2) void gemm_kv(const u16* __restrict__ A,
    const u16* __restrict__ BT, u16* __restrict__ Ck, u16* __restrict__ Cvt,
    int M, int N, int K) {
  extern __shared__ __attribute__((aligned(16))) u16 DL[];  // 3 x 12288 u16
  const int tid = threadIdx.x;
  const int nbx = N >> 7;                          // 16
  const int cpx = gridDim.x >> 3;
  const int swzb = (blockIdx.x & 7) * cpx + (blockIdx.x >> 3);
  const int bn0 = (swzb % nbx) << 7, bm0 = (swzb / nbx) << 8;
  const int l = tid & 63, g = l >> 4, q = l & 15;
  const int w = tid >> 6;
  const int wm = (w >> 2) * 128, wn = (w & 3) * 32;
  const int nt = K >> 5;
  f32x4 acc[8][2] = {};

  const int srow = tid >> 2, schunk = tid & 3;
  const int ssw = (schunk ^ ((srow >> 1) & 3)) << 3;
  const u16* gA0 = A  + (size_t)(bm0 + srow) * K + ssw;
  const u16* gA1 = gA0 + (size_t)128 * K;
  const u16* gB0 = BT + (size_t)(bn0 + srow) * K + ssw;

  auto STAGE = [&](int t) {
    const int kt = t << 5;
    u16* d = DL + (t % 3) * 12288;
    GLDS16(gA0 + kt, d + tid * 8);
    GLDS16(gA1 + kt, d + 4096 + tid * 8);
    GLDS16(gB0 + kt, d + 8192 + tid * 8);
  };

  const u16* ra = DL + (wm + q) * 32 + ((g ^ (((wm + q) >> 1) & 3)) << 3);
  const u16* rb = DL + 8192 + (wn + q) * 32 + ((g ^ (((wn + q) >> 1) & 3)) << 3);

  bf16x8 aC[8], aN[8], bC[2], bN[2];

  STAGE(0); STAGE(1);
  asm volatile("s_waitcnt vmcnt(3)" ::: "memory");
  __builtin_amdgcn_s_barrier();
  #pragma unroll
  for (int m = 0; m < 8; ++m) aC[m] = *(const bf16x8*)(ra + m * 512);
  #pragma unroll
  for (int n = 0; n < 2; ++n) bC[n] = *(const bf16x8*)(rb + n * 512);

  auto TILE = [&](int t, bf16x8 (&ac)[8], bf16x8 (&bc)[2],
                         bf16x8 (&an)[8], bf16x8 (&bn)[2]) {
    if (t + 2 < nt) {
      STAGE(t + 2);
      asm volatile("s_waitcnt vmcnt(3)" ::: "memory");
    } else {
      asm volatile("s_waitcnt vmcnt(0)" ::: "memory");
    }
    __builtin_amdgcn_s_barrier();
    if (t + 1 < nt) {
      const u16* pa = ra + ((t + 1) % 3) * 12288;
      const u16* pb = rb + ((t + 1) % 3) * 12288;
      #pragma unroll
      for (int m = 0; m < 8; ++m) an[m] = *(const bf16x8*)(pa + m * 512);
      #pragma unroll
      for (int n = 0; n < 2; ++n) bn[n] = *(const bf16x8*)(pb + n * 512);
    }
    __builtin_amdgcn_s_setprio(1);
    #pragma unroll
    for (int m = 0; m < 8; ++m) {
      acc[m][0] = mfma16(ac[m], bc[0], acc[m][0]);
      acc[m][1] = mfma16(ac[m], bc[1], acc[m][1]);
    }
    __builtin_amdgcn_s_setprio(0);
  };

  for (int t = 0; t < nt; t += 2) {
    TILE(t,     aC, bC, aN, bN);
    TILE(t + 1, aN, bN, aC, bC);
  }

  #pragma unroll
  for (int m = 0; m < 8; ++m)
    #pragma unroll
    for (int n = 0; n < 2; ++n) {
      int row0 = bm0 + wm + m * 16 + g * 4;
      int col  = bn0 + wn + n * 16 + q;
      if (col < 1024) {
        #pragma unroll
        for (int j = 0; j < 4; ++j)
          Ck[(size_t)(row0 + j) * 1024 + col] = f2bf(acc[m][n][j]);
      } else {
        int c2 = col - 1024;
        u16x4 pk;
        #pragma unroll
        for (int j = 0; j < 4; ++j) pk[j] = f2bf(acc[m][n][j]);
        size_t off = ((size_t)((row0 >> 11) * KV_ + (c2 >> 7)) * 32 + ((row0 >> 6) & 31)) * 8192
                   + (size_t)(c2 & 127) * 64 + (row0 & 63);
        *(u16x4*)(Cvt + off) = pk;
      }
    }
}

// ---------------- RoPE (interleaved pairs, in-place on bf16) ----------------
__global__ __launch_bounds__(256) void rope_kernel(u16* __restrict__ t,
    const float* __restrict__ fc, const float* __restrict__ fs,
    int log2ppr, int total_pairs) {
  int i = blockIdx.x * 256 + threadIdx.x;
  if (i >= total_pairs) return;
  int fi = i & 63;
  int row = i >> log2ppr;           // b*S + s
  int pos = row & (S_ - 1);
  float c = fc[pos * 64 + fi], s = fs[pos * 64 + fi];
  unsigned* p = (unsigned*)(t + 2 * (size_t)i);
  unsigned v = *p;
  float x0 = bf2f((u16)(v & 0xffffu)), x1 = bf2f((u16)(v >> 16));
  float r0 = x0 * c - x1 * s, r1 = x0 * s + x1 * c;
  *p = (unsigned)f2bf(r0) | ((unsigned)f2bf(r1) << 16);
}

// ---------------- causal GQA flash attention (swapped-QK^T) ----------------
// REVERTED to R11 (138us measured). grid (16,H,B)=1024 blocks=4/CU; 4 waves;
// QT=64 (16 q-rows/wave), pairing {31-p, p} -> uniform 33 KT=64 iters/block.
// R12/R13 lessons: (a) launch_bounds arg2 caps VGPR at 512/N -- (256,8) = 32
// VGPR = mass spill; (b) 8-blocks/CU via grid=capacity kills backfill ->
// imbalance dominates; KT=32 doubles per-iter sync overhead. Pairing at
// 4 blocks/CU is the local optimum for this structure.
__global__ __launch_bounds__(256, 4) void attn_kernel(
    const u16* __restrict__ Qb, const u16* __restrict__ Kb,
    const u16* __restrict__ VTg, u16* __restrict__ Ob) {
  __shared__ __attribute__((aligned(16))) u16 SM[20480]; // 40KB
  u16* Ks = SM;            // [64][128] swz(row&7)
  u16* Vs = SM + 8192;     // [128][64] swz(row&7)
  u16* Ps = SM + 16384;    // 4 waves x [16 q][64 k], 16B-chunk ^ (q&7)
  const int pr = blockIdx.x;            // 0..15
  const int h = blockIdx.y, b = blockIdx.z;
  const int kvh = h >> 2;               // N_REP = 4
  const int tid = threadIdx.x, w = tid >> 6, l = tid & 63, g = l >> 4, ql = l & 15;
  const float SL2E = 0.08838834764831845f * 1.4426950408889634f;
  const u16* Qh = Qb + (size_t)b * S_ * NQ_ + h * HD_;
  const u16* Kh = Kb + ((size_t)b * S_ * KV_ + kvh) * HD_;
  const u16* Vh = VTg + (size_t)(b * KV_ + kvh) * (32 * 8192);
  u16* Oh = Ob + (size_t)b * S_ * NQ_ + h * HD_;

  for (int ph = 0; ph < 2; ++ph) {
    const int qt = ph ? pr : 31 - pr;
    __syncthreads();   // SM (epilogue scratch) free before restaging
    bf16x8 aq[4];
    #pragma unroll
    for (int kk = 0; kk < 4; ++kk)
      aq[kk] = *(const bf16x8*)(Qh + (size_t)(qt * 64 + w * 16 + ql) * NQ_ + kk * 32 + g * 8);

    f32x4 o[8] = {};
    float mrow = -3.0e38f, lrow = 0.f;

    const int nkt = qt + 1;
    for (int kt = 0; kt < nkt; ++kt) {
      #pragma unroll
      for (int p = 0; p < 4; ++p) {   // K: [64][128]
        int c = tid + p * 256;
        int row = c >> 4, slot = c & 15;
        GLDS16(Kh + (size_t)(kt * 64 + row) * (KV_ * HD_) + ((slot ^ (row & 7)) << 3), Ks + c * 8);
      }
      #pragma unroll
      for (int p = 0; p < 4; ++p) {   // V^T: [128][64] from contiguous 16KB tile
        int c = tid + p * 256;
        int row = c >> 3, slot = c & 7;
        GLDS16(Vh + (size_t)kt * 8192 + row * 64 + ((slot ^ (row & 7)) << 3), Vs + c * 8);
      }
      asm volatile("s_waitcnt vmcnt(0)" ::: "memory");
      __builtin_amdgcn_s_barrier();

      if (kt * 64 <= qt * 64 + w * 16 + 15) {   // wave-uniform activity gate
        // ---- S^T = K * Q^T ----
        f32x4 sc[4] = {};
        #pragma unroll
        for (int kk = 0; kk < 4; ++kk) {
          bf16x8 bk[4];
          #pragma unroll
          for (int n = 0; n < 4; ++n) {
            int row = n * 16 + ql;
            bk[n] = *(const bf16x8*)(Ks + row * 128 + (((kk * 4 + g) ^ (row & 7)) << 3));
          }
          #pragma unroll
          for (int n = 0; n < 4; ++n)
            sc[n] = mfma16(bk[n], aq[kk], sc[n]);
        }
        // ---- causal mask (diagonal tiles only); lane holds k=kt*64+n*16+g*4+j, q=ql ----
        const int qglob = qt * 64 + w * 16 + ql;
        if (kt * 64 + 63 > qt * 64 + w * 16) {
          #pragma unroll
          for (int n = 0; n < 4; ++n)
            #pragma unroll
            for (int j = 0; j < 4; ++j)
              if (kt * 64 + n * 16 + g * 4 + j > qglob) sc[n][j] = -3.0e38f;
        }
        // ---- online softmax: in-lane over 16 k-vals, then xor16/xor32 ----
        float mx = sc[0][0];
        #pragma unroll
        for (int n = 0; n < 4; ++n)
          #pragma unroll
          for (int j = 0; j < 4; ++j) mx = fmaxf(mx, sc[n][j]);
        mx = fmaxf(mx, __shfl_xor(mx, 16));
        mx = fmaxf(mx, __shfl_xor(mx, 32));
        if (!__all(mx - mrow <= 16.0f)) {      // defer-max: P bounded by 2^2.04
          float mnew = fmaxf(mrow, mx);
          float f = exp2f((mrow - mnew) * SL2E);
          lrow *= f;
          #pragma unroll
          for (int m = 0; m < 8; ++m) o[m] *= f;
          mrow = mnew;
        }
        float rs = 0.f;
        #pragma unroll
        for (int n = 0; n < 4; ++n)
          #pragma unroll
          for (int j = 0; j < 4; ++j) {
            float pv = exp2f((sc[n][j] - mrow) * SL2E);
            sc[n][j] = pv; rs += pv;
          }
        rs += __shfl_xor(rs, 16);
        rs += __shfl_xor(rs, 32);
        lrow += rs;
        // ---- P -> LDS: [16 q][64 k], 16B chunk ^ (q&7); 4 x u16x4 writes ----
        u16* Pw = Ps + w * 1024;
        #pragma unroll
        for (int n = 0; n < 4; ++n) {
          u16x4 pk;
          #pragma unroll
          for (int j = 0; j < 4; ++j) pk[j] = f2bft(sc[n][j]);
          *(u16x4*)(Pw + ql * 64 + (((n * 2 + (g >> 1)) ^ (ql & 7)) << 3) + (g & 1) * 4) = pk;
        }
        // ---- PV: O^T = V^T * P^T ----
        #pragma unroll
        for (int kk2 = 0; kk2 < 2; ++kk2) {
          bf16x8 bp = *(const bf16x8*)(Pw + ql * 64 + (((kk2 * 4 + g) ^ (ql & 7)) << 3));
          #pragma unroll
          for (int m = 0; m < 8; ++m) {
            int row = m * 16 + ql;
            bf16x8 av = *(const bf16x8*)(Vs + row * 64 + (((kk2 * 4 + g) ^ (row & 7)) << 3));
            o[m] = mfma16(av, bp, o[m]);
          }
        }
      }
      __builtin_amdgcn_s_barrier();   // all waves done with Ks/Vs before restage
    }
    // ---- epilogue: normalize (lane-local), transpose via LDS, store ----
    __syncthreads();
    u16* OS = SM; // [64][136]
    float linv = 1.0f / lrow;
    #pragma unroll
    for (int m = 0; m < 8; ++m)
      #pragma unroll
      for (int j = 0; j < 4; ++j)
        OS[(w * 16 + ql) * 136 + m * 16 + g * 4 + j] = f2bf(o[m][j] * linv);
    __syncthreads();
    #pragma unroll
    for (int p = 0; p < 4; ++p) {
      int c = tid + p * 256;
      int row = c >> 4, col8 = c & 15;
      u16x8 d = *(const u16x8*)(OS + row * 136 + col8 * 8);
      *(u16x8*)(Oh + (size_t)(qt * 64 + row) * NQ_ + col8 * 8) = d;
    }
  }
}

extern "C" void kernel_launch(void* const* d_in, const int* in_sizes, int n_in,
                              void* d_out, int out_size, void* d_ws, size_t ws_size,
                              hipStream_t stream) {
  const float* x  = (const float*)d_in[0];
  const float* fc = (const float*)d_in[1];
  const float* fs = (const float*)d_in[2];
  // d_in[3] = mask (causal, applied analytically)
  const float* wq = (const float*)d_in[4];
  const float* wk = (const float*)d_in[5];
  const float* wv = (const float*)d_in[6];
  const float* wo = (const float*)d_in[7];

  char* ws = (char*)d_ws;
  u16* xb  = (u16*)(ws + 0);          // 33554432 B
  u16* wqT = (u16*)(ws + 33554432);   // 33554432
  u16* wkT = (u16*)(ws + 67108864);   // 8388608   (wkT||wvT = [2048][4096])
  u16* wvT = (u16*)(ws + 75497472);   // 8388608
  u16* woT = (u16*)(ws + 83886080);   // 33554432
  u16* qb  = (u16*)(ws + 117440512);  // 33554432
  u16* kb  = (u16*)(ws + 150994944);  // 8388608
  u16* vtg = (u16*)(ws + 159383552);  // 8388608  (V^T tiled: [B][KV][32][128][64])
  u16* ob  = (u16*)(ws + 167772160);  // 33554432  -> total 201326592
  if (ws_size < 201326592u) return;

  cvt_bf16<<<(M_ * D_) / (8 * 256), 256, 0, stream>>>(x, xb, M_ * D_);
  tcvt<<<dim3(NQ_ / 64, D_ / 64), 256, 0, stream>>>(wq, wqT, D_, NQ_);
  tcvt<<<dim3(NKV_ / 64, D_ / 64), 256, 0, stream>>>(wk, wkT, D_, NKV_);
  tcvt<<<dim3(NKV_ / 64, D_ / 64), 256, 0, stream>>>(wv, wvT, D_, NKV_);
  tcvt<<<dim3(D_ / 64, NQ_ / 64), 256, 0, stream>>>(wo, woT, NQ_, D_);

  gemm256<0><<<(NQ_ / 256) * (M_ / 256), 512, 98304, stream>>>(xb, wqT, qb, M_, NQ_, D_);
  // fused K+V projection: N=2048 (wkT||wvT contiguous), 256x128-tile pipeline
  gemm_kv<<<(2048 / 128) * (M_ / 256), 512, 73728, stream>>>(xb, wkT, kb, vtg, M_, 2048, D_);

  rope_kernel<<<(M_ * NQ_ / 2) / 256, 256, 0, stream>>>(qb, fc, fs, 11, M_ * NQ_ / 2);
  rope_kernel<<<(M_ * NKV_ / 2) / 256, 256, 0, stream>>>(kb, fc, fs, 9, M_ * NKV_ / 2);

  attn_kernel<<<dim3(16, H_, B_), 256, 0, stream>>>(qb, kb, vtg, ob);

  gemm256<1><<<(D_ / 256) * (M_ / 256), 512, 98304, stream>>>(ob, woT, d_out, M_, D_, NQ_);
}

// Round 15
// 516.629 us; speedup vs baseline: 2.1157x; 1.0192x over previous
//
#include <hip/hip_runtime.h>
#include <stdint.h>

#define B_ 2
#define S_ 2048
#define D_ 4096
#define H_ 32
#define KV_ 8
#define HD_ 128
#define M_ (B_*S_)          // 4096 rows (b*S+s)
#define NQ_ (H_*HD_)        // 4096
#define NKV_ (KV_*HD_)      // 1024

typedef unsigned short u16;
typedef __bf16 bf16x8 __attribute__((ext_vector_type(8)));
typedef float f32x4 __attribute__((ext_vector_type(4)));
typedef u16 u16x8 __attribute__((ext_vector_type(8)));
typedef u16 u16x4 __attribute__((ext_vector_type(4)));

__device__ __forceinline__ u16 f2bf(float f) {
  union { float f; unsigned u; } v; v.f = f;
  unsigned r = v.u + 0x7fffu + ((v.u >> 16) & 1u);
  return (u16)(r >> 16);
}
__device__ __forceinline__ u16 f2bft(float f) {  // truncating (for P; values in [0,4.2])
  union { float f; unsigned u; } v; v.f = f;
  return (u16)(v.u >> 16);
}
__device__ __forceinline__ float bf2f(u16 u) {
  union { unsigned u; float f; } v; v.u = ((unsigned)u) << 16;
  return v.f;
}
__device__ __forceinline__ f32x4 mfma16(bf16x8 a, bf16x8 b, f32x4 c) {
  return __builtin_amdgcn_mfma_f32_16x16x32_bf16(a, b, c, 0, 0, 0);
}

#define GLDS16(gp, lp) __builtin_amdgcn_global_load_lds( \
    (const __attribute__((address_space(1))) unsigned int*)(gp), \
    (__attribute__((address_space(3))) unsigned int*)(lp), 16, 0, 0)

// ---------------- fp32 -> bf16 convert (vectorized) ----------------
__global__ __launch_bounds__(256) void cvt_bf16(const float* __restrict__ in,
                                                u16* __restrict__ out, int n) {
  int i = (blockIdx.x * 256 + threadIdx.x) * 8;
  if (i >= n) return;
  float4 a = *(const float4*)(in + i);
  float4 b = *(const float4*)(in + i + 4);
  u16x8 o;
  o[0]=f2bf(a.x); o[1]=f2bf(a.y); o[2]=f2bf(a.z); o[3]=f2bf(a.w);
  o[4]=f2bf(b.x); o[5]=f2bf(b.y); o[6]=f2bf(b.z); o[7]=f2bf(b.w);
  *(u16x8*)(out + i) = o;
}

// -------- transpose + convert: out[c][r] = in[r][c], 64x64, vectorized --------
__global__ __launch_bounds__(256) void tcvt(const float* __restrict__ in,
                                            u16* __restrict__ out, int R, int C) {
  __shared__ float tf[64][65];
  int c0 = blockIdx.x * 64, r0 = blockIdx.y * 64;
  int l16 = threadIdx.x & 15, r16 = threadIdx.x >> 4;
  #pragma unroll
  for (int p = 0; p < 4; ++p) {
    int r = p * 16 + r16;
    float4 v = *(const float4*)(in + (size_t)(r0 + r) * C + c0 + l16 * 4);
    tf[r][l16 * 4 + 0] = v.x; tf[r][l16 * 4 + 1] = v.y;
    tf[r][l16 * 4 + 2] = v.z; tf[r][l16 * 4 + 3] = v.w;
  }
  __syncthreads();
  int oc = threadIdx.x >> 2, ch = threadIdx.x & 3;
  u16x8 o1, o2;
  #pragma unroll
  for (int i = 0; i < 8; ++i) o1[i] = f2bf(tf[ch * 16 + i][oc]);
  #pragma unroll
  for (int i = 0; i < 8; ++i) o2[i] = f2bf(tf[ch * 16 + 8 + i][oc]);
  *(u16x8*)(out + (size_t)(c0 + oc) * R + r0 + ch * 16) = o1;
  *(u16x8*)(out + (size_t)(c0 + oc) * R + r0 + ch * 16 + 8) = o2;
}

// ------- 256x256 GEMM, 3-buf rotation + FULL cross-tile register pipeline -------
// (R10 structure, ~1015 TF.) DOROPE: fused RoPE in epilogue -- pair (col even,
// col+1) = lanes (l, l^1); partner via shfl_xor(1); r = own*c + par*s*sgn
// (even: -par*s; odd: +par*s). pos = row & 2047, fi = (col&127)>>1 lane-fixed.
template<int OUTMODE, bool DOROPE>
__global__ __launch_bounds__(512, 2) void gemm256(const u16* __restrict__ A,
    const u16* __restrict__ BT, void* __restrict__ Cv,
    const float* __restrict__ FC, const float* __restrict__ FS,
    int M, int N, int K) {
  extern __shared__ __attribute__((aligned(16))) u16 DL[];  // 3 x 16384 u16
  const int tid = threadIdx.x;
  const int nbx = N >> 8;
  const int cpx = gridDim.x >> 3;                 // grid % 8 == 0
  const int swzb = (blockIdx.x & 7) * cpx + (blockIdx.x >> 3);
  const int bn0 = (swzb % nbx) << 8, bm0 = (swzb / nbx) << 8;
  const int l = tid & 63, g = l >> 4, q = l & 15;
  const int w = tid >> 6;
  const int wm = (w >> 2) * 128, wn = (w & 3) * 64;
  const int nt = K >> 5;   // BK = 32
  f32x4 acc[8][4] = {};

  const int srow = tid >> 2, schunk = tid & 3;
  const int ssw = (schunk ^ ((srow >> 1) & 3)) << 3;
  const u16* gA0 = A  + (size_t)(bm0 + srow) * K + ssw;
  const u16* gA1 = gA0 + (size_t)128 * K;
  const u16* gB0 = BT + (size_t)(bn0 + srow) * K + ssw;
  const u16* gB1 = gB0 + (size_t)128 * K;

  auto STAGE = [&](int t) {
    const int kt = t << 5;
    u16* d = DL + (t % 3) * 16384;
    GLDS16(gA0 + kt, d + tid * 8);
    GLDS16(gA1 + kt, d + 4096 + tid * 8);
    GLDS16(gB0 + kt, d + 8192 + tid * 8);
    GLDS16(gB1 + kt, d + 12288 + tid * 8);
  };

  const u16* ra = DL + (wm + q) * 32 + ((g ^ (((wm + q) >> 1) & 3)) << 3);
  const u16* rb = DL + 8192 + (wn + q) * 32 + ((g ^ (((wn + q) >> 1) & 3)) << 3);

  bf16x8 aC[8], aN[8], bC[4], bN[4];

  STAGE(0); STAGE(1);
  asm volatile("s_waitcnt vmcnt(4)" ::: "memory");
  __builtin_amdgcn_s_barrier();
  #pragma unroll
  for (int m = 0; m < 8; ++m) aC[m] = *(const bf16x8*)(ra + m * 512);
  #pragma unroll
  for (int n = 0; n < 4; ++n) bC[n] = *(const bf16x8*)(rb + n * 512);

  auto TILE = [&](int t, bf16x8 (&ac)[8], bf16x8 (&bc)[4],
                         bf16x8 (&an)[8], bf16x8 (&bn)[4]) {
    if (t + 2 < nt) {
      STAGE(t + 2);
      asm volatile("s_waitcnt vmcnt(4)" ::: "memory");
    } else {
      asm volatile("s_waitcnt vmcnt(0)" ::: "memory");
    }
    __builtin_amdgcn_s_barrier();
    if (t + 1 < nt) {
      const u16* pa = ra + ((t + 1) % 3) * 16384;
      const u16* pb = rb + ((t + 1) % 3) * 16384;
      #pragma unroll
      for (int m = 0; m < 8; ++m) an[m] = *(const bf16x8*)(pa + m * 512);
      #pragma unroll
      for (int n = 0; n < 4; ++n) bn[n] = *(const bf16x8*)(pb + n * 512);
    }
    __builtin_amdgcn_s_setprio(1);
    #pragma unroll
    for (int m = 0; m < 8; ++m) {
      acc[m][0] = mfma16(ac[m], bc[0], acc[m][0]);
      acc[m][1] = mfma16(ac[m], bc[1], acc[m][1]);
      acc[m][2] = mfma16(ac[m], bc[2], acc[m][2]);
      acc[m][3] = mfma16(ac[m], bc[3], acc[m][3]);
    }
    __builtin_amdgcn_s_setprio(0);
  };

  for (int t = 0; t < nt; t += 2) {
    TILE(t,     aC, bC, aN, bN);
    TILE(t + 1, aN, bN, aC, bC);
  }

  #pragma unroll
  for (int m = 0; m < 8; ++m)
    #pragma unroll
    for (int n = 0; n < 4; ++n) {
      const int col = bn0 + wn + n * 16 + q;
      if (DOROPE) {
        const int fi = (col & 127) >> 1;
        const float sgn = (q & 1) ? 1.0f : -1.0f;
        #pragma unroll
        for (int j = 0; j < 4; ++j) {
          int row = bm0 + wm + m * 16 + g * 4 + j;
          int pos = row & (S_ - 1);
          float c = FC[pos * 64 + fi], s = FS[pos * 64 + fi];
          float own = acc[m][n][j];
          float par = __shfl_xor(own, 1);
          ((u16*)Cv)[(size_t)row * N + col] = f2bf(own * c + par * s * sgn);
        }
      } else {
        #pragma unroll
        for (int j = 0; j < 4; ++j) {
          size_t off = (size_t)(bm0 + wm + m * 16 + g * 4 + j) * N + col;
          if (OUTMODE == 1) ((float*)Cv)[off] = acc[m][n][j];
          else              ((u16*)Cv)[off]  = f2bf(acc[m][n][j]);
        }
      }
    }
}

// ------- KV projection GEMM: BM=256 x BN=128, 3-buf reg pipeline -------
// K branch (col<1024): fused RoPE (same lane-pair scheme). V branch: plain.
__global__ __launch_bounds__(512, 2) void gemm_kv(const u16* __restrict__ A,
    const u16* __restrict__ BT, u16* __restrict__ Ck, u16* __restrict__ Cvt,
    const float* __restrict__ FC, const float* __restrict__ FS,
    int M, int N, int K) {
  extern __shared__ __attribute__((aligned(16))) u16 DL[];  // 3 x 12288 u16
  const int tid = threadIdx.x;
  const int nbx = N >> 7;                          // 16
  const int cpx = gridDim.x >> 3;
  const int swzb = (blockIdx.x & 7) * cpx + (blockIdx.x >> 3);
  const int bn0 = (swzb % nbx) << 7, bm0 = (swzb / nbx) << 8;
  const int l = tid & 63, g = l >> 4, q = l & 15;
  const int w = tid >> 6;
  const int wm = (w >> 2) * 128, wn = (w & 3) * 32;
  const int nt = K >> 5;
  f32x4 acc[8][2] = {};

  const int srow = tid >> 2, schunk = tid & 3;
  const int ssw = (schunk ^ ((srow >> 1) & 3)) << 3;
  const u16* gA0 = A  + (size_t)(bm0 + srow) * K + ssw;
  const u16* gA1 = gA0 + (size_t)128 * K;
  const u16* gB0 = BT + (size_t)(bn0 + srow) * K + ssw;

  auto STAGE = [&](int t) {
    const int kt = t << 5;
    u16* d = DL + (t % 3) * 12288;
    GLDS16(gA0 + kt, d + tid * 8);
    GLDS16(gA1 + kt, d + 4096 + tid * 8);
    GLDS16(gB0 + kt, d + 8192 + tid * 8);
  };

  const u16* ra = DL + (wm + q) * 32 + ((g ^ (((wm + q) >> 1) & 3)) << 3);
  const u16* rb = DL + 8192 + (wn + q) * 32 + ((g ^ (((wn + q) >> 1) & 3)) << 3);

  bf16x8 aC[8], aN[8], bC[2], bN[2];

  STAGE(0); STAGE(1);
  asm volatile("s_waitcnt vmcnt(3)" ::: "memory");
  __builtin_amdgcn_s_barrier();
  #pragma unroll
  for (int m = 0; m < 8; ++m) aC[m] = *(const bf16x8*)(ra + m * 512);
  #pragma unroll
  for (int n = 0; n < 2; ++n) bC[n] = *(const bf16x8*)(rb + n * 512);

  auto TILE = [&](int t, bf16x8 (&ac)[8], bf16x8 (&bc)[2],
                         bf16x8 (&an)[8], bf16x8 (&bn)[2]) {
    if (t + 2 < nt) {
      STAGE(t + 2);
      asm volatile("s_waitcnt vmcnt(3)" ::: "memory");
    } else {
      asm volatile("s_waitcnt vmcnt(0)" ::: "memory");
    }
    __builtin_amdgcn_s_barrier();
    if (t + 1 < nt) {
      const u16* pa = ra + ((t + 1) % 3) * 12288;
      const u16* pb = rb + ((t + 1) % 3) * 12288;
      #pragma unroll
      for (int m = 0; m < 8; ++m) an[m] = *(const bf16x8*)(pa + m * 512);
      #pragma unroll
      for (int n = 0; n < 2; ++n) bn[n] = *(const bf16x8*)(pb + n * 512);
    }
    __builtin_amdgcn_s_setprio(1);
    #pragma unroll
    for (int m = 0; m < 8; ++m) {
      acc[m][0] = mfma16(ac[m], bc[0], acc[m][0]);
      acc[m][1] = mfma16(ac[m], bc[1], acc[m][1]);
    }
    __builtin_amdgcn_s_setprio(0);
  };

  for (int t = 0; t < nt; t += 2) {
    TILE(t,     aC, bC, aN, bN);
    TILE(t + 1, aN, bN, aC, bC);
  }

  #pragma unroll
  for (int m = 0; m < 8; ++m)
    #pragma unroll
    for (int n = 0; n < 2; ++n) {
      int row0 = bm0 + wm + m * 16 + g * 4;
      int col  = bn0 + wn + n * 16 + q;
      if (col < 1024) {       // K head-cols: apply RoPE (uniform per 16-lane blk)
        const int fi = (col & 127) >> 1;
        const float sgn = (q & 1) ? 1.0f : -1.0f;
        #pragma unroll
        for (int j = 0; j < 4; ++j) {
          int row = row0 + j;
          int pos = row & (S_ - 1);
          float c = FC[pos * 64 + fi], s = FS[pos * 64 + fi];
          float own = acc[m][n][j];
          float par = __shfl_xor(own, 1);
          Ck[(size_t)row * 1024 + col] = f2bf(own * c + par * s * sgn);
        }
      } else {
        int c2 = col - 1024;
        u16x4 pk;
        #pragma unroll
        for (int j = 0; j < 4; ++j) pk[j] = f2bf(acc[m][n][j]);
        size_t off = ((size_t)((row0 >> 11) * KV_ + (c2 >> 7)) * 32 + ((row0 >> 6) & 31)) * 8192
                   + (size_t)(c2 & 127) * 64 + (row0 & 63);
        *(u16x4*)(Cvt + off) = pk;
      }
    }
}

// ---------------- causal GQA flash attention (swapped-QK^T) ----------------
// R11 version (138us measured). grid (16,H,B)=1024 blocks=4/CU; 4 waves;
// QT=64 (16 q-rows/wave), pairing {31-p, p} -> uniform 33 KT=64 iters/block.
// Lessons: launch_bounds arg2 caps VGPR at 512/N (R12: (256,8)=32 VGPR=spill);
// grid=capacity kills backfill (R13). Pairing at 4 blocks/CU is the optimum.
__global__ __launch_bounds__(256, 4) void attn_kernel(
    const u16* __restrict__ Qb, const u16* __restrict__ Kb,
    const u16* __restrict__ VTg, u16* __restrict__ Ob) {
  __shared__ __attribute__((aligned(16))) u16 SM[20480]; // 40KB
  u16* Ks = SM;            // [64][128] swz(row&7)
  u16* Vs = SM + 8192;     // [128][64] swz(row&7)
  u16* Ps = SM + 16384;    // 4 waves x [16 q][64 k], 16B-chunk ^ (q&7)
  const int pr = blockIdx.x;            // 0..15
  const int h = blockIdx.y, b = blockIdx.z;
  const int kvh = h >> 2;               // N_REP = 4
  const int tid = threadIdx.x, w = tid >> 6, l = tid & 63, g = l >> 4, ql = l & 15;
  const float SL2E = 0.08838834764831845f * 1.4426950408889634f;
  const u16* Qh = Qb + (size_t)b * S_ * NQ_ + h * HD_;
  const u16* Kh = Kb + ((size_t)b * S_ * KV_ + kvh) * HD_;
  const u16* Vh = VTg + (size_t)(b * KV_ + kvh) * (32 * 8192);
  u16* Oh = Ob + (size_t)b * S_ * NQ_ + h * HD_;

  for (int ph = 0; ph < 2; ++ph) {
    const int qt = ph ? pr : 31 - pr;
    __syncthreads();   // SM (epilogue scratch) free before restaging
    bf16x8 aq[4];
    #pragma unroll
    for (int kk = 0; kk < 4; ++kk)
      aq[kk] = *(const bf16x8*)(Qh + (size_t)(qt * 64 + w * 16 + ql) * NQ_ + kk * 32 + g * 8);

    f32x4 o[8] = {};
    float mrow = -3.0e38f, lrow = 0.f;

    const int nkt = qt + 1;
    for (int kt = 0; kt < nkt; ++kt) {
      #pragma unroll
      for (int p = 0; p < 4; ++p) {   // K: [64][128]
        int c = tid + p * 256;
        int row = c >> 4, slot = c & 15;
        GLDS16(Kh + (size_t)(kt * 64 + row) * (KV_ * HD_) + ((slot ^ (row & 7)) << 3), Ks + c * 8);
      }
      #pragma unroll
      for (int p = 0; p < 4; ++p) {   // V^T: [128][64] from contiguous 16KB tile
        int c = tid + p * 256;
        int row = c >> 3, slot = c & 7;
        GLDS16(Vh + (size_t)kt * 8192 + row * 64 + ((slot ^ (row & 7)) << 3), Vs + c * 8);
      }
      asm volatile("s_waitcnt vmcnt(0)" ::: "memory");
      __builtin_amdgcn_s_barrier();

      if (kt * 64 <= qt * 64 + w * 16 + 15) {   // wave-uniform activity gate
        // ---- S^T = K * Q^T ----
        f32x4 sc[4] = {};
        #pragma unroll
        for (int kk = 0; kk < 4; ++kk) {
          bf16x8 bk[4];
          #pragma unroll
          for (int n = 0; n < 4; ++n) {
            int row = n * 16 + ql;
            bk[n] = *(const bf16x8*)(Ks + row * 128 + (((kk * 4 + g) ^ (row & 7)) << 3));
          }
          #pragma unroll
          for (int n = 0; n < 4; ++n)
            sc[n] = mfma16(bk[n], aq[kk], sc[n]);
        }
        // ---- causal mask (diagonal tiles only); lane holds k=kt*64+n*16+g*4+j, q=ql ----
        const int qglob = qt * 64 + w * 16 + ql;
        if (kt * 64 + 63 > qt * 64 + w * 16) {
          #pragma unroll
          for (int n = 0; n < 4; ++n)
            #pragma unroll
            for (int j = 0; j < 4; ++j)
              if (kt * 64 + n * 16 + g * 4 + j > qglob) sc[n][j] = -3.0e38f;
        }
        // ---- online softmax: in-lane over 16 k-vals, then xor16/xor32 ----
        float mx = sc[0][0];
        #pragma unroll
        for (int n = 0; n < 4; ++n)
          #pragma unroll
          for (int j = 0; j < 4; ++j) mx = fmaxf(mx, sc[n][j]);
        mx = fmaxf(mx, __shfl_xor(mx, 16));
        mx = fmaxf(mx, __shfl_xor(mx, 32));
        if (!__all(mx - mrow <= 16.0f)) {      // defer-max: P bounded by 2^2.04
          float mnew = fmaxf(mrow, mx);
          float f = exp2f((mrow - mnew) * SL2E);
          lrow *= f;
          #pragma unroll
          for (int m = 0; m < 8; ++m) o[m] *= f;
          mrow = mnew;
        }
        float rs = 0.f;
        #pragma unroll
        for (int n = 0; n < 4; ++n)
          #pragma unroll
          for (int j = 0; j < 4; ++j) {
            float pv = exp2f((sc[n][j] - mrow) * SL2E);
            sc[n][j] = pv; rs += pv;
          }
        rs += __shfl_xor(rs, 16);
        rs += __shfl_xor(rs, 32);
        lrow += rs;
        // ---- P -> LDS: [16 q][64 k], 16B chunk ^ (q&7); 4 x u16x4 writes ----
        u16* Pw = Ps + w * 1024;
        #pragma unroll
        for (int n = 0; n < 4; ++n) {
          u16x4 pk;
          #pragma unroll
          for (int j = 0; j < 4; ++j) pk[j] = f2bft(sc[n][j]);
          *(u16x4*)(Pw + ql * 64 + (((n * 2 + (g >> 1)) ^ (ql & 7)) << 3) + (g & 1) * 4) = pk;
        }
        // ---- PV: O^T = V^T * P^T ----
        #pragma unroll
        for (int kk2 = 0; kk2 < 2; ++kk2) {
          bf16x8 bp = *(const bf16x8*)(Pw + ql * 64 + (((kk2 * 4 + g) ^ (ql & 7)) << 3));
          #pragma unroll
          for (int m = 0; m < 8; ++m) {
            int row = m * 16 + ql;
            bf16x8 av = *(const bf16x8*)(Vs + row * 64 + (((kk2 * 4 + g) ^ (row & 7)) << 3));
            o[m] = mfma16(av, bp, o[m]);
          }
        }
      }
      __builtin_amdgcn_s_barrier();   // all waves done with Ks/Vs before restage
    }
    // ---- epilogue: normalize (lane-local), transpose via LDS, store ----
    __syncthreads();
    u16* OS = SM; // [64][136]
    float linv = 1.0f / lrow;
    #pragma unroll
    for (int m = 0; m < 8; ++m)
      #pragma unroll
      for (int j = 0; j < 4; ++j)
        OS[(w * 16 + ql) * 136 + m * 16 + g * 4 + j] = f2bf(o[m][j] * linv);
    __syncthreads();
    #pragma unroll
    for (int p = 0; p < 4; ++p) {
      int c = tid + p * 256;
      int row = c >> 4, col8 = c & 15;
      u16x8 d = *(const u16x8*)(OS + row * 136 + col8 * 8);
      *(u16x8*)(Oh + (size_t)(qt * 64 + row) * NQ_ + col8 * 8) = d;
    }
  }
}

extern "C" void kernel_launch(void* const* d_in, const int* in_sizes, int n_in,
                              void* d_out, int out_size, void* d_ws, size_t ws_size,
                              hipStream_t stream) {
  const float* x  = (const float*)d_in[0];
  const float* fc = (const float*)d_in[1];
  const float* fs = (const float*)d_in[2];
  // d_in[3] = mask (causal, applied analytically)
  const float* wq = (const float*)d_in[4];
  const float* wk = (const float*)d_in[5];
  const float* wv = (const float*)d_in[6];
  const float* wo = (const float*)d_in[7];

  char* ws = (char*)d_ws;
  u16* xb  = (u16*)(ws + 0);          // 33554432 B
  u16* wqT = (u16*)(ws + 33554432);   // 33554432
  u16* wkT = (u16*)(ws + 67108864);   // 8388608   (wkT||wvT = [2048][4096])
  u16* wvT = (u16*)(ws + 75497472);   // 8388608
  u16* woT = (u16*)(ws + 83886080);   // 33554432
  u16* qb  = (u16*)(ws + 117440512);  // 33554432
  u16* kb  = (u16*)(ws + 150994944);  // 8388608
  u16* vtg = (u16*)(ws + 159383552);  // 8388608  (V^T tiled: [B][KV][32][128][64])
  u16* ob  = (u16*)(ws + 167772160);  // 33554432  -> total 201326592
  if (ws_size < 201326592u) return;

  cvt_bf16<<<(M_ * D_) / (8 * 256), 256, 0, stream>>>(x, xb, M_ * D_);
  tcvt<<<dim3(NQ_ / 64, D_ / 64), 256, 0, stream>>>(wq, wqT, D_, NQ_);
  tcvt<<<dim3(NKV_ / 64, D_ / 64), 256, 0, stream>>>(wk, wkT, D_, NKV_);
  tcvt<<<dim3(NKV_ / 64, D_ / 64), 256, 0, stream>>>(wv, wvT, D_, NKV_);
  tcvt<<<dim3(D_ / 64, NQ_ / 64), 256, 0, stream>>>(wo, woT, NQ_, D_);

  // Q projection + fused RoPE
  gemm256<0, true><<<(NQ_ / 256) * (M_ / 256), 512, 98304, stream>>>(
      xb, wqT, qb, fc, fs, M_, NQ_, D_);
  // fused K+V projection (K branch: fused RoPE; V: tiled V^T layout)
  gemm_kv<<<(2048 / 128) * (M_ / 256), 512, 73728, stream>>>(
      xb, wkT, kb, vtg, fc, fs, M_, 2048, D_);

  attn_kernel<<<dim3(16, H_, B_), 256, 0, stream>>>(qb, kb, vtg, ob);

  gemm256<1, false><<<(D_ / 256) * (M_ / 256), 512, 98304, stream>>>(
      ob, woT, d_out, fc, fs, M_, D_, NQ_);
}